// Round 6
// baseline (168.642 us; speedup 1.0000x reference)
//
#include <hip/hip_runtime.h>
#include <hip/hip_bf16.h>

// NormPool2d: 3x3 reflect-padded window, output = mean - unbiased std.
// x: (16, 96, 224, 224) fp32 -> out same shape, fp32.
//
// Round 5b: same as round 5 (fill-kernel shape: no per-thread loop, one
// thread = 4 outputs of one row, 75264 blocks = 18 residency batches),
// with the nontemporal store fixed to use a native ext_vector_type
// (the builtin rejects HIP's float4 wrapper class).

#define NP_W 224
#define NP_H 224
#define NP_PLANES (16 * 96)
#define NP_STRIPS (NP_W / 4)                 // 56
#define NP_TPP (NP_STRIPS * NP_H)            // 12544 threads per plane
#define NP_BPP (NP_TPP / 256)                // 49 blocks per plane

typedef float f32x4 __attribute__((ext_vector_type(4)));

__global__ __launch_bounds__(256) void NormPool2d_kernel(
    const float* __restrict__ x, float* __restrict__ out) {
    const int W = NP_W, H = NP_H;
    int t = blockIdx.x * 256 + threadIdx.x;  // [0, 12544) within plane
    int plane = blockIdx.y;
    int strip = t % NP_STRIPS;
    int h = t / NP_STRIPS;                   // output row
    int w = strip * 4;

    const float* __restrict__ xp = x + (size_t)plane * (H * W);
    const bool le = (w == 0);
    const bool re = (w == W - 4);

    int hm = (h == 0) ? 1 : h - 1;           // reflect: row -1 -> 1
    int hp = (h == H - 1) ? H - 2 : h + 1;   // reflect: row H -> H-2

    // Issue all 9 loads up front (3 rows x {float4, left, right}).
    const float* r0 = xp + (size_t)hm * W;
    const float* r1 = xp + (size_t)h * W;
    const float* r2 = xp + (size_t)hp * W;
    float4 v0 = *reinterpret_cast<const float4*>(r0 + w);
    float4 v1 = *reinterpret_cast<const float4*>(r1 + w);
    float4 v2 = *reinterpret_cast<const float4*>(r2 + w);
    float l0 = le ? v0.y : r0[w - 1];
    float l1 = le ? v1.y : r1[w - 1];
    float l2 = le ? v2.y : r2[w - 1];
    float t0 = re ? v0.z : r0[w + 4];
    float t1 = re ? v1.z : r1[w + 4];
    float t2 = re ? v2.z : r2[w + 4];

    // Column sums over the 3 rows (6 columns: l, x, y, z, w, r).
    float cl = l0 + l1 + l2;
    float ca = v0.x + v1.x + v2.x;
    float cb = v0.y + v1.y + v2.y;
    float cc = v0.z + v1.z + v2.z;
    float cd = v0.w + v1.w + v2.w;
    float cr = t0 + t1 + t2;
    float ql = l0 * l0 + l1 * l1 + l2 * l2;
    float qa = v0.x * v0.x + v1.x * v1.x + v2.x * v2.x;
    float qb = v0.y * v0.y + v1.y * v1.y + v2.y * v2.y;
    float qc = v0.z * v0.z + v1.z * v1.z + v2.z * v2.z;
    float qd = v0.w * v0.w + v1.w * v1.w + v2.w * v2.w;
    float qr = t0 * t0 + t1 * t1 + t2 * t2;

    auto finish = [](float s, float q) -> float {
        float mean = s * (1.f / 9.f);
        float var = (q - s * mean) * 0.125f;  // unbiased: (ss - s^2/9)/8
        return mean - __builtin_amdgcn_sqrtf(fmaxf(var, 0.f));
    };

    f32x4 o;
    o.x = finish(cl + ca + cb, ql + qa + qb);
    o.y = finish(ca + cb + cc, qa + qb + qc);
    o.z = finish(cb + cc + cd, qb + qc + qd);
    o.w = finish(cc + cd + cr, qc + qd + qr);

    f32x4* dst = reinterpret_cast<f32x4*>(out + (size_t)plane * (H * W) +
                                          (size_t)h * W + w);
    __builtin_nontemporal_store(o, dst);
}

extern "C" void kernel_launch(void* const* d_in, const int* in_sizes, int n_in,
                              void* d_out, int out_size, void* d_ws, size_t ws_size,
                              hipStream_t stream) {
    const float* x = (const float*)d_in[0];
    float* out = (float*)d_out;
    (void)in_sizes; (void)n_in; (void)out_size; (void)d_ws; (void)ws_size;

    dim3 grid(NP_BPP, NP_PLANES, 1);  // 49 x 1536 = 75264 blocks
    NormPool2d_kernel<<<grid, dim3(256, 1, 1), 0, stream>>>(x, out);
}

// Round 7
// 143.235 us; speedup vs baseline: 1.1774x; 1.1774x over previous
//
#include <hip/hip_runtime.h>
#include <hip/hip_bf16.h>

// NormPool2d: 3x3 reflect-padded window, output = mean - unbiased std.
// x: (16, 96, 224, 224) fp32 -> out same shape, fp32.
//
// Round 7: all prior rounds (147-188us) fit one model: waves serialize
// load-burst -> latency wait -> compute, so HBM never sees continuous
// pressure (VALU ~33%, HBM ~35%, time invariant to occupancy/chain/inst
// count). This round:
//  - wave-per-row: lane = float4 strip (56 active of 64). Horizontal
//    neighbor taps via __shfl of the vertically-summed columns (sum and
//    shuffle commute): 4 shuffles, ZERO scalar loads, zero unaligned
//    requests. W-edge reflect coincides with wave edge -> no cross-wave dep.
//  - persistent grid-stride + depth-2 register prefetch: 2048 blocks
//    (8/CU, one residency batch), 42 tasks/wave exactly; next task's 3
//    row loads are issued before current task's compute -> loads stay
//    outstanding for the kernel's whole life.
// Per task: 3x 896B coalesced loads + 1x 896B NT store.

#define NP_W 224
#define NP_H 224
#define NP_PLANES 1536
#define NP_PLSZ (NP_H * NP_W)          // 50176
#define NP_TASKS (NP_PLANES * NP_H)    // 344064 (plane,row) wave-tasks
#define NP_GRID 2048
#define NP_WAVES (NP_GRID * 4)         // 8192
#define NP_ITERS (NP_TASKS / NP_WAVES) // 42 exactly

typedef float f32x4 __attribute__((ext_vector_type(4)));

struct Task { const float *ra, *rb, *rc; float* o; };

__device__ __forceinline__ Task mk_task(int t, const float* __restrict__ x,
                                        float* __restrict__ out, int w) {
    int h = t % NP_H;
    int p = t / NP_H;
    int hm = (h == 0) ? 1 : h - 1;           // reflect row -1 -> 1
    int hp = (h == NP_H - 1) ? NP_H - 2 : h + 1;  // reflect row H -> H-2
    size_t pb = (size_t)p * NP_PLSZ + w;
    Task k;
    k.ra = x + pb + (size_t)hm * NP_W;
    k.rb = x + pb + (size_t)h * NP_W;
    k.rc = x + pb + (size_t)hp * NP_W;
    k.o = out + pb + (size_t)h * NP_W;
    return k;
}

__device__ __forceinline__ float fin(float s, float q) {
    float mean = s * (1.f / 9.f);
    float var = (q - s * mean) * 0.125f;  // unbiased: (ss - s^2/9)/8
    return mean - __builtin_amdgcn_sqrtf(fmaxf(var, 0.f));
}

__global__ __launch_bounds__(256) void NormPool2d_kernel(
    const float* __restrict__ x, float* __restrict__ out) {
    int wid = (blockIdx.x * 256 + (int)threadIdx.x) >> 6;  // [0, 8192)
    int lane = threadIdx.x & 63;
    int s = (lane < 56) ? lane : 55;   // clamp dup lanes (same line, free)
    int w = s * 4;
    bool active = (lane < 56);

    int t = wid;
    Task cur = mk_task(t, x, out, w);
    f32x4 a0 = *reinterpret_cast<const f32x4*>(cur.ra);
    f32x4 a1 = *reinterpret_cast<const f32x4*>(cur.rb);
    f32x4 a2 = *reinterpret_cast<const f32x4*>(cur.rc);

    #pragma unroll 1
    for (int i = 0; i < NP_ITERS; ++i) {
        // ---- prefetch next task (uniform clamp on last iter) ----
        int tn = t + NP_WAVES;
        if (tn >= NP_TASKS) tn = t;
        Task nxt = mk_task(tn, x, out, w);
        f32x4 b0 = *reinterpret_cast<const f32x4*>(nxt.ra);
        f32x4 b1 = *reinterpret_cast<const f32x4*>(nxt.rb);
        f32x4 b2 = *reinterpret_cast<const f32x4*>(nxt.rc);

        // ---- compute current task ----
        f32x4 sv = a0 + a1 + a2;                       // column sums
        f32x4 sq = a0 * a0 + a1 * a1 + a2 * a2;        // column sumsq

        // horizontal neighbor columns from adjacent lanes
        float lf_s = __shfl_up(sv.w, 1);
        float lf_q = __shfl_up(sq.w, 1);
        float rt_s = __shfl_down(sv.x, 1);
        float rt_q = __shfl_down(sq.x, 1);
        if (s == 0)  { lf_s = sv.y; lf_q = sq.y; }     // reflect col -1 -> 1
        if (s == 55) { rt_s = sv.z; rt_q = sq.z; }     // reflect col W -> W-2

        f32x4 o;
        o.x = fin(lf_s + sv.x + sv.y, lf_q + sq.x + sq.y);
        o.y = fin(sv.x + sv.y + sv.z, sq.x + sq.y + sq.z);
        o.z = fin(sv.y + sv.z + sv.w, sq.y + sq.z + sq.w);
        o.w = fin(sv.z + sv.w + rt_s, sq.z + sq.w + rt_q);

        if (active) {
            __builtin_nontemporal_store(o, reinterpret_cast<f32x4*>(cur.o));
        }

        // ---- rotate pipeline ----
        cur = nxt;
        a0 = b0; a1 = b1; a2 = b2;
        t = tn;
    }
}

extern "C" void kernel_launch(void* const* d_in, const int* in_sizes, int n_in,
                              void* d_out, int out_size, void* d_ws, size_t ws_size,
                              hipStream_t stream) {
    const float* x = (const float*)d_in[0];
    float* out = (float*)d_out;
    (void)in_sizes; (void)n_in; (void)out_size; (void)d_ws; (void)ws_size;

    NormPool2d_kernel<<<NP_GRID, 256, 0, stream>>>(x, out);
}

// Round 10
// 103.868 us; speedup vs baseline: 1.6236x; 1.3790x over previous
//
#include <hip/hip_runtime.h>
#include <hip/hip_bf16.h>

// NormPool2d: 3x3 reflect-padded window, output = mean - unbiased std.
// x: (16, 96, 224, 224) fp32 -> out same shape, fp32.
//
// Round 10: R8/R9's register-slot asm pipelines were structurally unsound
// (regalloc copies race in-flight loads; guide r282). This round uses the
// guide's PROVEN async mechanism: __builtin_amdgcn_global_load_lds --
// in-flight data lands in LDS, not registers, so the compiler cannot
// collapse the pipeline and regalloc cannot race it. m97-style structure:
//   loop: stage(next chunk -> other LDS buffer)   [async, 4 instrs]
//         compute(current chunk from LDS)          [covers the latency]
//         __syncthreads()                          [compiler vmcnt drain]
// 16-output-row chunks (18 staged rows, reflect applied at stage time),
// double-buffered: 2 x 16 KiB LDS. 1024 blocks = exactly 4/CU uniform
// residency; 21 chunks/block (1536 planes x 14 chunks). Compute = R7's
// proven wave-per-row shfl math, rows read from LDS as ds_read_b128.

#define NP_W 224
#define NP_H 224
#define NP_PLSZ (NP_H * NP_W)        // floats per plane
#define NP_ROWB 896                  // bytes per row
#define NP_CPP 14                    // chunks per plane (14*16 = 224)
#define NP_CH_OUT 16                 // output rows per chunk
#define NP_CH_IN 18                  // staged rows per chunk
#define NP_BUF 16384                 // padded buffer bytes (4 x 4096)
#define NP_GRID 1024
#define NP_ITERS 21                  // 1536*14 / 1024

typedef float f32x4 __attribute__((ext_vector_type(4)));

__device__ __forceinline__ float fin(float s, float q) {
    float mean = s * (1.f / 9.f);
    float var = (q - s * mean) * 0.125f;  // unbiased: (ss - s^2/9)/8
    return mean - __builtin_amdgcn_sqrtf(fmaxf(var, 0.f));
}

__global__ __launch_bounds__(256) void NormPool2d_kernel(
    const float* __restrict__ x, float* __restrict__ out) {
    __shared__ alignas(16) char smem[2 * NP_BUF];  // 32 KiB
    const int tid = (int)threadIdx.x;
    const int lane = tid & 63;
    const int wave = tid >> 6;
    const int sl = (lane < 56) ? lane : 55;  // clamp dup lanes
    const bool act = (lane < 56);

    // ---- stage chunk cc's 18 input rows into LDS buffer at bufbase ----
    auto stage = [&](int cc, int bufbase) {
        int plane = cc / NP_CPP;
        int sub = cc - plane * NP_CPP;
        int h0 = sub * NP_CH_OUT;
        const char* xplane =
            (const char*)(x + (size_t)plane * NP_PLSZ);
        #pragma unroll
        for (int j = 0; j < 4; ++j) {
            int off = j * 4096 + tid * 16;      // byte offset in buffer
            int r0 = off / NP_ROWB;             // staged row index 0..18
            int col = off - r0 * NP_ROWB;       // byte col within row
            int r = (r0 > NP_CH_IN - 1) ? NP_CH_IN - 1 : r0;  // pad clamp
            int g = h0 - 1 + r;                 // global row of slot r
            g = (g < 0) ? 1 : g;                // reflect top: -1 -> 1
            g = (g > NP_H - 1) ? NP_H - 2 : g;  // reflect bottom: 224 -> 222
            const float* src =
                (const float*)(xplane + (size_t)g * NP_ROWB + col);
            float* dst = (float*)(smem + bufbase + j * 4096 + wave * 1024);
            __builtin_amdgcn_global_load_lds(src, dst, 16, 0, 0);
        }
    };

    // ---- compute chunk cc's 16 output rows from LDS buffer ----
    auto compute = [&](int cc, int bufbase) {
        int plane = cc / NP_CPP;
        int sub = cc - plane * NP_CPP;
        int h0 = sub * NP_CH_OUT;
        float* oplane = out + (size_t)plane * NP_PLSZ;
        #pragma unroll
        for (int q = 0; q < 4; ++q) {
            int lr = wave * 4 + q;              // output row within chunk
            const char* base = smem + bufbase + (size_t)lr * NP_ROWB + sl * 16;
            f32x4 a0 = *(const f32x4*)(base);             // row h-1
            f32x4 a1 = *(const f32x4*)(base + NP_ROWB);   // row h
            f32x4 a2 = *(const f32x4*)(base + 2 * NP_ROWB);  // row h+1
            f32x4 sv = a0 + a1 + a2;
            f32x4 sq = a0 * a0 + a1 * a1 + a2 * a2;
            float lf_s = __shfl_up(sv.w, 1);
            float lf_q = __shfl_up(sq.w, 1);
            float rt_s = __shfl_down(sv.x, 1);
            float rt_q = __shfl_down(sq.x, 1);
            if (sl == 0)  { lf_s = sv.y; lf_q = sq.y; }  // reflect w=-1 -> 1
            if (sl == 55) { rt_s = sv.z; rt_q = sq.z; }  // reflect w=W -> W-2
            f32x4 o;
            o.x = fin(lf_s + sv.x + sv.y, lf_q + sq.x + sq.y);
            o.y = fin(sv.x + sv.y + sv.z, sq.x + sq.y + sq.z);
            o.z = fin(sv.y + sv.z + sv.w, sq.y + sq.z + sq.w);
            o.w = fin(sv.z + sv.w + rt_s, sq.z + sq.w + rt_q);
            if (act) {
                f32x4* dst = (f32x4*)(oplane +
                    (size_t)(h0 + lr) * NP_W + sl * 4);
                __builtin_nontemporal_store(o, dst);
            }
        }
    };

    int c = blockIdx.x;
    stage(c, 0);
    __syncthreads();

    #pragma unroll 1
    for (int i = 0; i < NP_ITERS; ++i) {
        int cur = (i & 1) * NP_BUF;
        if (i < NP_ITERS - 1) stage(c + NP_GRID, cur ^ NP_BUF);
        __builtin_amdgcn_sched_barrier(0);  // keep stage issued before compute
        compute(c, cur);
        __syncthreads();  // drains vmcnt -> next buffer ready; reads done
        c += NP_GRID;
    }
}

extern "C" void kernel_launch(void* const* d_in, const int* in_sizes, int n_in,
                              void* d_out, int out_size, void* d_ws, size_t ws_size,
                              hipStream_t stream) {
    const float* x = (const float*)d_in[0];
    float* out = (float*)d_out;
    (void)in_sizes; (void)n_in; (void)out_size; (void)d_ws; (void)ws_size;

    NormPool2d_kernel<<<NP_GRID, 256, 0, stream>>>(x, out);
}